// Round 9
// baseline (353.444 us; speedup 1.0000x reference)
//
#include <hip/hip_runtime.h>

#define N_NODES 100000
#define N_EDGES 1600000
#define D 128

typedef unsigned short ushort_t;
struct ushort4_t { ushort_t x, y, z, w; };
typedef float vf2 __attribute__((ext_vector_type(2)));
typedef __attribute__((ext_vector_type(8))) short bf16x8;
typedef __attribute__((ext_vector_type(4))) float f32x4;

__device__ __forceinline__ ushort_t f2bf(float f) {
    unsigned u = __float_as_uint(f);
    unsigned r = (u + 0x7fffu + ((u >> 16) & 1u)) >> 16;   // RNE
    return (ushort_t)r;
}
__device__ __forceinline__ float bf2f(ushort_t b) {
    return __uint_as_float(((unsigned)b) << 16);
}

// ---------------- Kernel 1: LayerNorm + ReLU -> bf16 h ---------------------------
__global__ __launch_bounds__(256) void ln_relu_kernel(
    const float* __restrict__ x, const float* __restrict__ gamma,
    const float* __restrict__ beta, ushort_t* __restrict__ hb)
{
    int wave   = threadIdx.x >> 6;
    int half   = (threadIdx.x >> 5) & 1;
    int lane32 = threadIdx.x & 31;
    int row = blockIdx.x * 8 + wave * 2 + half;
    float4 v = ((const float4*)(x + (size_t)row * D))[lane32];
    float s  = (v.x + v.y) + (v.z + v.w);
    float sq = (v.x * v.x + v.y * v.y) + (v.z * v.z + v.w * v.w);
#pragma unroll
    for (int m = 16; m >= 1; m >>= 1) {
        s  += __shfl_xor(s, m);
        sq += __shfl_xor(sq, m);
    }
    float mu   = s * (1.0f / D);
    float var  = sq * (1.0f / D) - mu * mu;
    float rstd = rsqrtf(var + 1e-5f);
    float4 g = ((const float4*)gamma)[lane32];
    float4 b = ((const float4*)beta)[lane32];
    ushort4_t o;
    o.x = f2bf(fmaxf(fmaf((v.x - mu) * rstd, g.x, b.x), 0.0f));
    o.y = f2bf(fmaxf(fmaf((v.y - mu) * rstd, g.y, b.y), 0.0f));
    o.z = f2bf(fmaxf(fmaf((v.z - mu) * rstd, g.z, b.z), 0.0f));
    o.w = f2bf(fmaxf(fmaf((v.w - mu) * rstd, g.w, b.w), 0.0f));
    *(ushort4_t*)(hb + (size_t)row * D + lane32 * 4) = o;
}

// ---------------- Kernel 1b: detect edge dtype (int64 vs int32 view) ------------
__global__ void detect_kernel(const int* __restrict__ e, int* __restrict__ flag)
{
    int z = 1;
    for (int i = 1; i < 128; i += 2) z &= (e[i] == 0) ? 1 : 0;
    *flag = z;  // 1 => int64 layout
}

// ---------------- Kernel 1c: W -> bf16 (row-major, same layout) ------------------
__global__ __launch_bounds__(256) void wbf_kernel(
    const float* __restrict__ W, ushort_t* __restrict__ wbf)
{
    int i = (blockIdx.x * 256 + threadIdx.x) * 4;   // 16 blocks cover 16384
    float4 w = *(const float4*)(W + i);
    ushort4_t o;
    o.x = f2bf(w.x); o.y = f2bf(w.y); o.z = f2bf(w.z); o.w = f2bf(w.w);
    *(ushort4_t*)(wbf + i) = o;
}

// ---------------- Kernel 2: build per-dst chains + degree histogram --------------
__global__ __launch_bounds__(256) void chain_build_kernel(
    const void* __restrict__ e_raw, const int* __restrict__ flag,
    long long* __restrict__ chain, int* __restrict__ head, int* __restrict__ counts)
{
    int e = blockIdx.x * 256 + threadIdx.x;   // exactly N_EDGES threads
    int s, d;
    if (*flag) {
        s = (int)__builtin_nontemporal_load(&((const long long*)e_raw)[e]);
        d = (int)__builtin_nontemporal_load(&((const long long*)e_raw)[N_EDGES + e]);
    } else {
        s = __builtin_nontemporal_load(&((const int*)e_raw)[e]);
        d = __builtin_nontemporal_load(&((const int*)e_raw)[N_EDGES + e]);
    }
    int old = atomicExch(&head[d], e);
    atomicAdd(&counts[d], 1);
    chain[e] = (long long)(unsigned int)s | ((long long)old << 32);
}

// ---------------- Kernel 2b: per-block exclusive scan (chunk = 256) --------------
__global__ __launch_bounds__(256) void scan_partial_kernel(
    const int* __restrict__ counts, int* __restrict__ pre, int* __restrict__ bsum)
{
    int i = blockIdx.x * 256 + threadIdx.x;
    int v = (i < N_NODES) ? counts[i] : 0;
    int lane = threadIdx.x & 63, w = threadIdx.x >> 6;
    int s = v;
#pragma unroll
    for (int m = 1; m < 64; m <<= 1) {
        int t = __shfl_up(s, m);
        if (lane >= m) s += t;
    }
    __shared__ int wsum[4];
    if (lane == 63) wsum[w] = s;
    __syncthreads();
    if (threadIdx.x == 0) {
        int a = 0;
#pragma unroll
        for (int k = 0; k < 4; ++k) { int t = wsum[k]; wsum[k] = a; a += t; }
        bsum[blockIdx.x] = a;
    }
    __syncthreads();
    if (i < N_NODES) pre[i] = wsum[w] + (s - v);  // block-local exclusive
}

// ---------------- Kernel 2c: scan the 391 block sums (single block) --------------
__global__ __launch_bounds__(512) void scan_block_kernel(int* __restrict__ bsum, int nb)
{
    int i = threadIdx.x;
    int v = (i < nb) ? bsum[i] : 0;
    int lane = i & 63, w = i >> 6;
    int s = v;
#pragma unroll
    for (int m = 1; m < 64; m <<= 1) {
        int t = __shfl_up(s, m);
        if (lane >= m) s += t;
    }
    __shared__ int wsum[8];
    if (lane == 63) wsum[w] = s;
    __syncthreads();
    if (i == 0) {
        int a = 0;
#pragma unroll
        for (int k = 0; k < 8; ++k) { int t = wsum[k]; wsum[k] = a; a += t; }
    }
    __syncthreads();
    if (i < nb) bsum[i] = wsum[w] + (s - v);
}

// ---------------- Kernel 2d: offsets = pre + bsum --------------------------------
__global__ __launch_bounds__(256) void finalize_kernel(
    const int* __restrict__ pre, const int* __restrict__ bsum, int* __restrict__ offsets)
{
    int i = blockIdx.x * 256 + threadIdx.x;
    if (i < N_NODES)       offsets[i] = pre[i] + bsum[i >> 8];
    else if (i == N_NODES) offsets[i] = N_EDGES;
}

// ---------------- Kernel 2e: flatten chains into CSR src lists -------------------
// One thread per node: chase-only (full 100K-way MLP), sequential segment writes.
__global__ __launch_bounds__(256) void flatten_kernel(
    const long long* __restrict__ chain, const int* __restrict__ head,
    const int* __restrict__ offsets, int* __restrict__ csr)
{
    int n = blockIdx.x * 256 + threadIdx.x;
    if (n >= N_NODES) return;
    int e = head[n];
    int pos = offsets[n];
    while (e != -1) {
        long long c = chain[e];
        csr[pos++] = (int)(unsigned int)c;
        e = (int)(c >> 32);
    }
}

// ---------------- Kernel 3: CSR segment sum — one wave per node ------------------
// lane = one dword (2 bf16) of the row. srcs read 8-at-a-time via wave-uniform
// int4 loads (HW broadcast); 8 independent row-gathers in flight per iteration.
__global__ __launch_bounds__(256) void csr_segsum_kernel(
    const ushort_t* __restrict__ hb, const int* __restrict__ offsets,
    const int* __restrict__ csr, float* __restrict__ aggr)
{
    int n    = blockIdx.x * 4 + (threadIdx.x >> 6);
    int lane = threadIdx.x & 63;
    int e    = offsets[n];
    int eend = offsets[n + 1];
    const unsigned* hrow = (const unsigned*)hb;   // 64 dwords per node row
    float ax = 0.0f, ay = 0.0f;

    for (; e + 8 <= eend; e += 8) {
        int4 sa = *(const int4*)(csr + e);
        int4 sb = *(const int4*)(csr + e + 4);
        unsigned p0 = hrow[(size_t)sa.x * 64 + lane];
        unsigned p1 = hrow[(size_t)sa.y * 64 + lane];
        unsigned p2 = hrow[(size_t)sa.z * 64 + lane];
        unsigned p3 = hrow[(size_t)sa.w * 64 + lane];
        unsigned p4 = hrow[(size_t)sb.x * 64 + lane];
        unsigned p5 = hrow[(size_t)sb.y * 64 + lane];
        unsigned p6 = hrow[(size_t)sb.z * 64 + lane];
        unsigned p7 = hrow[(size_t)sb.w * 64 + lane];
        ax += bf2f((ushort_t)(p0 & 0xffffu)) + bf2f((ushort_t)(p1 & 0xffffu))
            + bf2f((ushort_t)(p2 & 0xffffu)) + bf2f((ushort_t)(p3 & 0xffffu))
            + bf2f((ushort_t)(p4 & 0xffffu)) + bf2f((ushort_t)(p5 & 0xffffu))
            + bf2f((ushort_t)(p6 & 0xffffu)) + bf2f((ushort_t)(p7 & 0xffffu));
        ay += bf2f((ushort_t)(p0 >> 16)) + bf2f((ushort_t)(p1 >> 16))
            + bf2f((ushort_t)(p2 >> 16)) + bf2f((ushort_t)(p3 >> 16))
            + bf2f((ushort_t)(p4 >> 16)) + bf2f((ushort_t)(p5 >> 16))
            + bf2f((ushort_t)(p6 >> 16)) + bf2f((ushort_t)(p7 >> 16));
    }
    for (; e < eend; ++e) {
        int s = csr[e];
        unsigned p = hrow[(size_t)s * 64 + lane];
        ax += bf2f((ushort_t)(p & 0xffffu));
        ay += bf2f((ushort_t)(p >> 16));
    }

    vf2 o = {ax, ay};
    __builtin_nontemporal_store(o, (vf2*)(aggr + (size_t)n * D + lane * 2));
}

// ---------------- Kernel 4: out = ((1+eps)h + aggr) @ W^T + b + x  (MFMA) --------
// aggr aliases out: each wave reads only its own 16 rows, writes them after.
__global__ __launch_bounds__(256) void gemm_mfma_kernel(
    const ushort_t* __restrict__ hb, const float* __restrict__ aggr,
    const float* __restrict__ x, const ushort_t* __restrict__ wbf,
    const float* __restrict__ bias, const float* __restrict__ eps_p,
    float* __restrict__ out)
{
    const int wv   = threadIdx.x >> 6;
    const int lane = threadIdx.x & 63;
    const int l16  = lane & 15;
    const int kg   = lane >> 4;                 // 0..3
    const int row  = blockIdx.x * 64 + wv * 16 + l16;
    const int rowc = row < N_NODES ? row : N_NODES - 1;
    const float ep1 = 1.0f + eps_p[0];

    f32x4 acc[8];
#pragma unroll
    for (int nt = 0; nt < 8; ++nt) acc[nt] = (f32x4){0.f, 0.f, 0.f, 0.f};

#pragma unroll
    for (int ks = 0; ks < 4; ++ks) {
        const int k0 = ks * 32 + kg * 8;
        const ushort_t* hp = hb   + (size_t)rowc * D + k0;
        const float*    ap = aggr + (size_t)rowc * D + k0;
        ushort4_t h0 = *(const ushort4_t*)(hp);
        ushort4_t h1 = *(const ushort4_t*)(hp + 4);
        float4 a0 = *(const float4*)(ap);
        float4 a1 = *(const float4*)(ap + 4);
        bf16x8 af;
        af[0] = (short)f2bf(fmaf(ep1, bf2f(h0.x), a0.x));
        af[1] = (short)f2bf(fmaf(ep1, bf2f(h0.y), a0.y));
        af[2] = (short)f2bf(fmaf(ep1, bf2f(h0.z), a0.z));
        af[3] = (short)f2bf(fmaf(ep1, bf2f(h0.w), a0.w));
        af[4] = (short)f2bf(fmaf(ep1, bf2f(h1.x), a1.x));
        af[5] = (short)f2bf(fmaf(ep1, bf2f(h1.y), a1.y));
        af[6] = (short)f2bf(fmaf(ep1, bf2f(h1.z), a1.z));
        af[7] = (short)f2bf(fmaf(ep1, bf2f(h1.w), a1.w));

#pragma unroll
        for (int nt = 0; nt < 8; ++nt) {
            bf16x8 bf = *(const bf16x8*)(wbf + (size_t)(nt * 16 + l16) * D + k0);
            acc[nt] = __builtin_amdgcn_mfma_f32_16x16x32_bf16(af, bf, acc[nt], 0, 0, 0);
        }
    }

#pragma unroll
    for (int nt = 0; nt < 8; ++nt) {
        int col = nt * 16 + l16;
        float bv = bias[col];
#pragma unroll
        for (int r = 0; r < 4; ++r) {
            int orow = blockIdx.x * 64 + wv * 16 + kg * 4 + r;
            if (orow < N_NODES) {
                float xv = __builtin_nontemporal_load(&x[(size_t)orow * D + col]);
                __builtin_nontemporal_store(acc[nt][r] + bv + xv,
                                            &out[(size_t)orow * D + col]);
            }
        }
    }
}

extern "C" void kernel_launch(void* const* d_in, const int* in_sizes, int n_in,
                              void* d_out, int out_size, void* d_ws, size_t ws_size,
                              hipStream_t stream)
{
    const float* x     = (const float*)d_in[0];
    const void*  ei    = d_in[1];
    const float* gamma = (const float*)d_in[2];
    const float* beta  = (const float*)d_in[3];
    const float* W     = (const float*)d_in[4];
    const float* bias  = (const float*)d_in[5];
    const float* eps_p = (const float*)d_in[6];
    float* out = (float*)d_out;

    char* ws = (char*)d_ws;
    size_t off = 0;
    ushort_t*  hb      = (ushort_t*)(ws + off);  off += (size_t)N_NODES * D * 2;   // 25.6 MB
    long long* chain   = (long long*)(ws + off); off += (size_t)N_EDGES * 8;       // 12.8 MB
    int*       csr     = (int*)(ws + off);       off += (size_t)N_EDGES * 4;       //  6.4 MB
    int*       head    = (int*)(ws + off);       off += (size_t)N_NODES * 4;       //  0.4 MB
    int*       counts  = (int*)(ws + off);       off += (size_t)N_NODES * 4;       //  0.4 MB
    int*       pre     = (int*)(ws + off);       off += (size_t)N_NODES * 4;       //  0.4 MB
    int*       offsets = (int*)(ws + off);       off += (size_t)(N_NODES + 4) * 4; //  0.4 MB
    int*       bsum    = (int*)(ws + off);       off += 512 * 4;
    ushort_t*  wbf     = (ushort_t*)(ws + off);  off += (size_t)D * D * 2;         //  32 KB
    int*       flag    = (int*)(ws + off);       off += 4;

    const int NB_SCAN = (N_NODES + 255) / 256;  // 391

    detect_kernel<<<1, 1, 0, stream>>>((const int*)ei, flag);
    (void)hipMemsetAsync(head, 0xFF, (size_t)N_NODES * 4, stream);     // head = -1
    (void)hipMemsetAsync(counts, 0, (size_t)N_NODES * 4, stream);
    chain_build_kernel<<<N_EDGES / 256, 256, 0, stream>>>(ei, flag, chain, head, counts);
    scan_partial_kernel<<<NB_SCAN, 256, 0, stream>>>(counts, pre, bsum);
    scan_block_kernel<<<1, 512, 0, stream>>>(bsum, NB_SCAN);
    finalize_kernel<<<(N_NODES + 256) / 256, 256, 0, stream>>>(pre, bsum, offsets);
    flatten_kernel<<<NB_SCAN, 256, 0, stream>>>(chain, head, offsets, csr);
    ln_relu_kernel<<<N_NODES / 8, 256, 0, stream>>>(x, gamma, beta, hb);
    wbf_kernel<<<16, 256, 0, stream>>>(W, wbf);
    csr_segsum_kernel<<<N_NODES / 4, 256, 0, stream>>>(hb, offsets, csr, out);
    gemm_mfma_kernel<<<(N_NODES + 63) / 64, 256, 0, stream>>>(hb, out, x, wbf, bias, eps_p, out);
}

// Round 10
// 294.504 us; speedup vs baseline: 1.2001x; 1.2001x over previous
//
#include <hip/hip_runtime.h>

#define N_NODES 100000
#define N_EDGES 1600000
#define D 128

typedef unsigned short ushort_t;
struct ushort4_t { ushort_t x, y, z, w; };
typedef __attribute__((ext_vector_type(8))) short bf16x8;
typedef __attribute__((ext_vector_type(4))) float f32x4;

__device__ __forceinline__ ushort_t f2bf(float f) {
    unsigned u = __float_as_uint(f);
    unsigned r = (u + 0x7fffu + ((u >> 16) & 1u)) >> 16;   // RNE
    return (ushort_t)r;
}
__device__ __forceinline__ float bf2f(ushort_t b) {
    return __uint_as_float(((unsigned)b) << 16);
}

// ---------------- Kernel 1: LayerNorm + ReLU -> bf16 h ---------------------------
__global__ __launch_bounds__(256) void ln_relu_kernel(
    const float* __restrict__ x, const float* __restrict__ gamma,
    const float* __restrict__ beta, ushort_t* __restrict__ hb)
{
    int wave   = threadIdx.x >> 6;
    int half   = (threadIdx.x >> 5) & 1;
    int lane32 = threadIdx.x & 31;
    int row = blockIdx.x * 8 + wave * 2 + half;
    float4 v = ((const float4*)(x + (size_t)row * D))[lane32];
    float s  = (v.x + v.y) + (v.z + v.w);
    float sq = (v.x * v.x + v.y * v.y) + (v.z * v.z + v.w * v.w);
#pragma unroll
    for (int m = 16; m >= 1; m >>= 1) {
        s  += __shfl_xor(s, m);
        sq += __shfl_xor(sq, m);
    }
    float mu   = s * (1.0f / D);
    float var  = sq * (1.0f / D) - mu * mu;
    float rstd = rsqrtf(var + 1e-5f);
    float4 g = ((const float4*)gamma)[lane32];
    float4 b = ((const float4*)beta)[lane32];
    ushort4_t o;
    o.x = f2bf(fmaxf(fmaf((v.x - mu) * rstd, g.x, b.x), 0.0f));
    o.y = f2bf(fmaxf(fmaf((v.y - mu) * rstd, g.y, b.y), 0.0f));
    o.z = f2bf(fmaxf(fmaf((v.z - mu) * rstd, g.z, b.z), 0.0f));
    o.w = f2bf(fmaxf(fmaf((v.w - mu) * rstd, g.w, b.w), 0.0f));
    *(ushort4_t*)(hb + (size_t)row * D + lane32 * 4) = o;
}

// ---------------- Kernel 1b: detect edge dtype (int64 vs int32 view) ------------
__global__ void detect_kernel(const int* __restrict__ e, int* __restrict__ flag)
{
    int z = 1;
    for (int i = 1; i < 128; i += 2) z &= (e[i] == 0) ? 1 : 0;
    *flag = z;  // 1 => int64 layout
}

// ---------------- Kernel 1c: W -> bf16 (row-major, same layout) ------------------
__global__ __launch_bounds__(256) void wbf_kernel(
    const float* __restrict__ W, ushort_t* __restrict__ wbf)
{
    int i = (blockIdx.x * 256 + threadIdx.x) * 4;   // 16 blocks cover 16384
    float4 w = *(const float4*)(W + i);
    ushort4_t o;
    o.x = f2bf(w.x); o.y = f2bf(w.y); o.z = f2bf(w.z); o.w = f2bf(w.w);
    *(ushort4_t*)(wbf + i) = o;
}

// ---------------- Kernel 2: build per-dst chains (exch-only) ---------------------
// chain[e] = src | (next << 32). ONE random atomic per edge; chain store coalesced.
__global__ __launch_bounds__(256) void chain_build_kernel(
    const void* __restrict__ e_raw, const int* __restrict__ flag,
    long long* __restrict__ chain, int* __restrict__ head)
{
    int e = blockIdx.x * 256 + threadIdx.x;   // exactly N_EDGES threads
    int s, d;
    if (*flag) {
        s = (int)__builtin_nontemporal_load(&((const long long*)e_raw)[e]);
        d = (int)__builtin_nontemporal_load(&((const long long*)e_raw)[N_EDGES + e]);
    } else {
        s = __builtin_nontemporal_load(&((const int*)e_raw)[e]);
        d = __builtin_nontemporal_load(&((const int*)e_raw)[N_EDGES + e]);
    }
    int old = atomicExch(&head[d], e);
    chain[e] = (long long)(unsigned int)s | ((long long)old << 32);
}

// ---------------- Kernel 2b: flatten chains -> CSR (no scan, no count atomics) ---
// One thread per node. Walk 1 counts deg; wave prefix-sum + ONE atomicAdd per wave
// (1563 total) allocates the segment; walk 2 writes srcs contiguously.
__global__ __launch_bounds__(256) void flatten2_kernel(
    const long long* __restrict__ chain, const int* __restrict__ head,
    int* __restrict__ cursor, int2* __restrict__ posdeg, int* __restrict__ csr)
{
    int n    = blockIdx.x * 256 + threadIdx.x;
    int lane = threadIdx.x & 63;
    int e = (n < N_NODES) ? head[n] : -1;

    // walk 1: count
    int deg = 0;
    int t = e;
    while (t != -1) {
        long long c = chain[t];
        ++deg;
        t = (int)(c >> 32);
    }

    // wave-aggregated allocation
    int psum = deg;
#pragma unroll
    for (int m = 1; m < 64; m <<= 1) {
        int v = __shfl_up(psum, m);
        if (lane >= m) psum += v;
    }
    int total = __shfl(psum, 63);
    int base = 0;
    if (lane == 0) base = atomicAdd(cursor, total);
    base = __shfl(base, 0);
    int pos = base + psum - deg;          // exclusive within wave
    if (n < N_NODES) posdeg[n] = make_int2(pos, deg);

    // walk 2: write
    int p = pos;
    while (e != -1) {
        long long c = chain[e];
        csr[p++] = (int)(unsigned int)c;
        e = (int)(c >> 32);
    }
}

// ---------------- Kernel 3: CSR segment sum — one wave per node, bf16 out --------
// lane = one dword (2 bf16) of the row; srcs read 8-at-a-time (wave-uniform int4
// broadcast); 8 independent row-gathers in flight per iteration.
__global__ __launch_bounds__(256) void csr_segsum_kernel(
    const ushort_t* __restrict__ hb, const int2* __restrict__ posdeg,
    const int* __restrict__ csr, ushort_t* __restrict__ aggrb)
{
    int n    = blockIdx.x * 4 + (threadIdx.x >> 6);
    int lane = threadIdx.x & 63;
    int2 pd  = posdeg[n];
    int e    = pd.x;
    int eend = pd.x + pd.y;
    const unsigned* hrow = (const unsigned*)hb;   // 64 dwords per node row
    float ax = 0.0f, ay = 0.0f;

    for (; e + 8 <= eend; e += 8) {
        int4 sa = *(const int4*)(csr + e);
        int4 sb = *(const int4*)(csr + e + 4);
        unsigned p0 = hrow[(size_t)sa.x * 64 + lane];
        unsigned p1 = hrow[(size_t)sa.y * 64 + lane];
        unsigned p2 = hrow[(size_t)sa.z * 64 + lane];
        unsigned p3 = hrow[(size_t)sa.w * 64 + lane];
        unsigned p4 = hrow[(size_t)sb.x * 64 + lane];
        unsigned p5 = hrow[(size_t)sb.y * 64 + lane];
        unsigned p6 = hrow[(size_t)sb.z * 64 + lane];
        unsigned p7 = hrow[(size_t)sb.w * 64 + lane];
        ax += bf2f((ushort_t)(p0 & 0xffffu)) + bf2f((ushort_t)(p1 & 0xffffu))
            + bf2f((ushort_t)(p2 & 0xffffu)) + bf2f((ushort_t)(p3 & 0xffffu))
            + bf2f((ushort_t)(p4 & 0xffffu)) + bf2f((ushort_t)(p5 & 0xffffu))
            + bf2f((ushort_t)(p6 & 0xffffu)) + bf2f((ushort_t)(p7 & 0xffffu));
        ay += bf2f((ushort_t)(p0 >> 16)) + bf2f((ushort_t)(p1 >> 16))
            + bf2f((ushort_t)(p2 >> 16)) + bf2f((ushort_t)(p3 >> 16))
            + bf2f((ushort_t)(p4 >> 16)) + bf2f((ushort_t)(p5 >> 16))
            + bf2f((ushort_t)(p6 >> 16)) + bf2f((ushort_t)(p7 >> 16));
    }
    for (; e < eend; ++e) {
        int s = csr[e];
        unsigned p = hrow[(size_t)s * 64 + lane];
        ax += bf2f((ushort_t)(p & 0xffffu));
        ay += bf2f((ushort_t)(p >> 16));
    }

    unsigned o = (unsigned)f2bf(ax) | ((unsigned)f2bf(ay) << 16);
    __builtin_nontemporal_store(o, (unsigned*)aggrb + (size_t)n * 64 + lane);
}

// ---------------- Kernel 4: out = ((1+eps)h + aggr) @ W^T + b + x  (MFMA) --------
// Block = 256 (4 waves); wave owns 16 rows x 128 cols; K=128 in 4 steps of 32.
// All operands bf16 global->reg; no LDS, no barriers.
// C/D: col = lane&15, row = (lane>>4)*4 + reg  [m89].
__global__ __launch_bounds__(256) void gemm_mfma_kernel(
    const ushort_t* __restrict__ hb, const ushort_t* __restrict__ aggrb,
    const float* __restrict__ x, const ushort_t* __restrict__ wbf,
    const float* __restrict__ bias, const float* __restrict__ eps_p,
    float* __restrict__ out)
{
    const int wv   = threadIdx.x >> 6;
    const int lane = threadIdx.x & 63;
    const int l16  = lane & 15;
    const int kg   = lane >> 4;                 // 0..3
    const int row  = blockIdx.x * 64 + wv * 16 + l16;
    const int rowc = row < N_NODES ? row : N_NODES - 1;
    const float ep1 = 1.0f + eps_p[0];

    f32x4 acc[8];
#pragma unroll
    for (int nt = 0; nt < 8; ++nt) acc[nt] = (f32x4){0.f, 0.f, 0.f, 0.f};

#pragma unroll
    for (int ks = 0; ks < 4; ++ks) {
        const int k0 = ks * 32 + kg * 8;
        const ushort_t* hp = hb    + (size_t)rowc * D + k0;
        const ushort_t* ap = aggrb + (size_t)rowc * D + k0;
        ushort4_t h0 = *(const ushort4_t*)(hp);
        ushort4_t h1 = *(const ushort4_t*)(hp + 4);
        ushort4_t a0 = *(const ushort4_t*)(ap);
        ushort4_t a1 = *(const ushort4_t*)(ap + 4);
        bf16x8 af;
        af[0] = (short)f2bf(fmaf(ep1, bf2f(h0.x), bf2f(a0.x)));
        af[1] = (short)f2bf(fmaf(ep1, bf2f(h0.y), bf2f(a0.y)));
        af[2] = (short)f2bf(fmaf(ep1, bf2f(h0.z), bf2f(a0.z)));
        af[3] = (short)f2bf(fmaf(ep1, bf2f(h0.w), bf2f(a0.w)));
        af[4] = (short)f2bf(fmaf(ep1, bf2f(h1.x), bf2f(a1.x)));
        af[5] = (short)f2bf(fmaf(ep1, bf2f(h1.y), bf2f(a1.y)));
        af[6] = (short)f2bf(fmaf(ep1, bf2f(h1.z), bf2f(a1.z)));
        af[7] = (short)f2bf(fmaf(ep1, bf2f(h1.w), bf2f(a1.w)));

#pragma unroll
        for (int nt = 0; nt < 8; ++nt) {
            bf16x8 bf = *(const bf16x8*)(wbf + (size_t)(nt * 16 + l16) * D + k0);
            acc[nt] = __builtin_amdgcn_mfma_f32_16x16x32_bf16(af, bf, acc[nt], 0, 0, 0);
        }
    }

#pragma unroll
    for (int nt = 0; nt < 8; ++nt) {
        int col = nt * 16 + l16;
        float bv = bias[col];
#pragma unroll
        for (int r = 0; r < 4; ++r) {
            int orow = blockIdx.x * 64 + wv * 16 + kg * 4 + r;
            if (orow < N_NODES) {
                float xv = __builtin_nontemporal_load(&x[(size_t)orow * D + col]);
                __builtin_nontemporal_store(acc[nt][r] + bv + xv,
                                            &out[(size_t)orow * D + col]);
            }
        }
    }
}

extern "C" void kernel_launch(void* const* d_in, const int* in_sizes, int n_in,
                              void* d_out, int out_size, void* d_ws, size_t ws_size,
                              hipStream_t stream)
{
    const float* x     = (const float*)d_in[0];
    const void*  ei    = d_in[1];
    const float* gamma = (const float*)d_in[2];
    const float* beta  = (const float*)d_in[3];
    const float* W     = (const float*)d_in[4];
    const float* bias  = (const float*)d_in[5];
    const float* eps_p = (const float*)d_in[6];
    float* out = (float*)d_out;

    char* ws = (char*)d_ws;
    size_t off = 0;
    ushort_t*  hb      = (ushort_t*)(ws + off);  off += (size_t)N_NODES * D * 2;   // 25.6 MB
    ushort_t*  aggrb   = (ushort_t*)(ws + off);  off += (size_t)N_NODES * D * 2;   // 25.6 MB
    long long* chain   = (long long*)(ws + off); off += (size_t)N_EDGES * 8;       // 12.8 MB
    int*       csr     = (int*)(ws + off);       off += (size_t)N_EDGES * 4;       //  6.4 MB
    int*       head    = (int*)(ws + off);       off += (size_t)N_NODES * 4;       //  0.4 MB
    int2*      posdeg  = (int2*)(ws + off);      off += (size_t)N_NODES * 8;       //  0.8 MB
    ushort_t*  wbf     = (ushort_t*)(ws + off);  off += (size_t)D * D * 2;         //  32 KB
    int*       cursor  = (int*)(ws + off);       off += 4;
    int*       flag    = (int*)(ws + off);       off += 4;

    detect_kernel<<<1, 1, 0, stream>>>((const int*)ei, flag);
    (void)hipMemsetAsync(head, 0xFF, (size_t)N_NODES * 4, stream);     // head = -1
    (void)hipMemsetAsync(cursor, 0, 4, stream);
    chain_build_kernel<<<N_EDGES / 256, 256, 0, stream>>>(ei, flag, chain, head);
    ln_relu_kernel<<<N_NODES / 8, 256, 0, stream>>>(x, gamma, beta, hb);
    wbf_kernel<<<16, 256, 0, stream>>>(W, wbf);
    flatten2_kernel<<<(N_NODES + 255) / 256, 256, 0, stream>>>(chain, head, cursor, posdeg, csr);
    csr_segsum_kernel<<<N_NODES / 4, 256, 0, stream>>>(hb, posdeg, csr, aggrb);
    gemm_mfma_kernel<<<(N_NODES + 63) / 64, 256, 0, stream>>>(hb, aggrb, x, wbf, bias, eps_p, out);
}

// Round 11
// 265.620 us; speedup vs baseline: 1.3306x; 1.1087x over previous
//
#include <hip/hip_runtime.h>

#define N_NODES 100000
#define N_EDGES 1600000
#define D 128

typedef unsigned short ushort_t;
struct ushort4_t { ushort_t x, y, z, w; };
typedef __attribute__((ext_vector_type(8))) short bf16x8;
typedef __attribute__((ext_vector_type(4))) float f32x4;
typedef float vf4 __attribute__((ext_vector_type(4)));

#define NB_CHAIN (N_EDGES / 256)          // 6250
#define NB_WBF   16
#define NB_FLAT  ((N_NODES + 255) / 256)  // 391
#define NB_LN    (N_NODES / 8)            // 12500

__device__ __forceinline__ ushort_t f2bf(float f) {
    unsigned u = __float_as_uint(f);
    unsigned r = (u + 0x7fffu + ((u >> 16) & 1u)) >> 16;   // RNE
    return (ushort_t)r;
}
__device__ __forceinline__ float bf2f(ushort_t b) {
    return __uint_as_float(((unsigned)b) << 16);
}

// ---------------- K1: chain_build (+inline dtype detect) | wbf ------------------
// chain[e] = src | (next << 32). ONE random atomic per edge; chain store coalesced.
__global__ __launch_bounds__(256) void build_wbf_kernel(
    const void* __restrict__ e_raw,
    long long* __restrict__ chain, int* __restrict__ head,
    const float* __restrict__ W, ushort_t* __restrict__ wbf)
{
    int b = blockIdx.x;
    if (b < NB_CHAIN) {
        // inline int64-vs-int32 detect: odd int32 words of first 64 entries all 0
        int li = threadIdx.x & 63;
        int probe = ((const int*)e_raw)[2 * li + 1];
        bool is64 = (__ballot(probe == 0) == ~0ULL);   // wave-uniform

        int e = b * 256 + threadIdx.x;                 // exactly N_EDGES threads
        int s, d;
        if (is64) {
            s = (int)__builtin_nontemporal_load(&((const long long*)e_raw)[e]);
            d = (int)__builtin_nontemporal_load(&((const long long*)e_raw)[N_EDGES + e]);
        } else {
            s = __builtin_nontemporal_load(&((const int*)e_raw)[e]);
            d = __builtin_nontemporal_load(&((const int*)e_raw)[N_EDGES + e]);
        }
        int old = atomicExch(&head[d], e);
        chain[e] = (long long)(unsigned int)s | ((long long)old << 32);
    } else {
        // wbf: W -> bf16, 16 blocks cover 128*128
        int i = ((b - NB_CHAIN) * 256 + threadIdx.x) * 4;
        float4 w = *(const float4*)(W + i);
        ushort4_t o;
        o.x = f2bf(w.x); o.y = f2bf(w.y); o.z = f2bf(w.z); o.w = f2bf(w.w);
        *(ushort4_t*)(wbf + i) = o;
    }
}

// ---------------- K2: flatten chains -> CSR | LayerNorm+ReLU -> bf16 h ----------
// flatten: one thread per node, walk 1 counts deg, wave prefix + 1 atomic/wave
// allocates, walk 2 writes srcs. ln: streaming BW hides under flatten latency.
__global__ __launch_bounds__(256) void flatten_ln_kernel(
    const long long* __restrict__ chain, const int* __restrict__ head,
    int* __restrict__ cursor, int2* __restrict__ posdeg, int* __restrict__ csr,
    const float* __restrict__ x, const float* __restrict__ gamma,
    const float* __restrict__ beta, ushort_t* __restrict__ hb)
{
    int b = blockIdx.x;
    if (b < NB_FLAT) {
        int n    = b * 256 + threadIdx.x;
        int lane = threadIdx.x & 63;
        int e = (n < N_NODES) ? head[n] : -1;

        // walk 1: count
        int deg = 0;
        int t = e;
        while (t != -1) {
            long long c = chain[t];
            ++deg;
            t = (int)(c >> 32);
        }

        // wave-aggregated allocation
        int psum = deg;
#pragma unroll
        for (int m = 1; m < 64; m <<= 1) {
            int v = __shfl_up(psum, m);
            if (lane >= m) psum += v;
        }
        int total = __shfl(psum, 63);
        int base = 0;
        if (lane == 0) base = atomicAdd(cursor, total);
        base = __shfl(base, 0);
        int pos = base + psum - deg;          // exclusive within wave
        if (n < N_NODES) posdeg[n] = make_int2(pos, deg);

        // walk 2: write
        int p = pos;
        while (e != -1) {
            long long c = chain[e];
            csr[p++] = (int)(unsigned int)c;
            e = (int)(c >> 32);
        }
    } else {
        int wave   = threadIdx.x >> 6;
        int half   = (threadIdx.x >> 5) & 1;
        int lane32 = threadIdx.x & 31;
        int row = (b - NB_FLAT) * 8 + wave * 2 + half;
        float4 v = ((const float4*)(x + (size_t)row * D))[lane32];
        float s  = (v.x + v.y) + (v.z + v.w);
        float sq = (v.x * v.x + v.y * v.y) + (v.z * v.z + v.w * v.w);
#pragma unroll
        for (int m = 16; m >= 1; m >>= 1) {
            s  += __shfl_xor(s, m);
            sq += __shfl_xor(sq, m);
        }
        float mu   = s * (1.0f / D);
        float var  = sq * (1.0f / D) - mu * mu;
        float rstd = rsqrtf(var + 1e-5f);
        float4 g = ((const float4*)gamma)[lane32];
        float4 bb = ((const float4*)beta)[lane32];
        ushort4_t o;
        o.x = f2bf(fmaxf(fmaf((v.x - mu) * rstd, g.x, bb.x), 0.0f));
        o.y = f2bf(fmaxf(fmaf((v.y - mu) * rstd, g.y, bb.y), 0.0f));
        o.z = f2bf(fmaxf(fmaf((v.z - mu) * rstd, g.z, bb.z), 0.0f));
        o.w = f2bf(fmaxf(fmaf((v.w - mu) * rstd, g.w, bb.w), 0.0f));
        *(ushort4_t*)(hb + (size_t)row * D + lane32 * 4) = o;
    }
}

// ---------------- K3: CSR segment sum — one wave per node, bf16 out --------------
__global__ __launch_bounds__(256) void csr_segsum_kernel(
    const ushort_t* __restrict__ hb, const int2* __restrict__ posdeg,
    const int* __restrict__ csr, ushort_t* __restrict__ aggrb)
{
    int n    = blockIdx.x * 4 + (threadIdx.x >> 6);
    int lane = threadIdx.x & 63;
    int2 pd  = posdeg[n];
    int e    = pd.x;
    int eend = pd.x + pd.y;
    const unsigned* hrow = (const unsigned*)hb;   // 64 dwords per node row
    float ax = 0.0f, ay = 0.0f;

    for (; e + 8 <= eend; e += 8) {
        int4 sa = *(const int4*)(csr + e);
        int4 sb = *(const int4*)(csr + e + 4);
        unsigned p0 = hrow[(size_t)sa.x * 64 + lane];
        unsigned p1 = hrow[(size_t)sa.y * 64 + lane];
        unsigned p2 = hrow[(size_t)sa.z * 64 + lane];
        unsigned p3 = hrow[(size_t)sa.w * 64 + lane];
        unsigned p4 = hrow[(size_t)sb.x * 64 + lane];
        unsigned p5 = hrow[(size_t)sb.y * 64 + lane];
        unsigned p6 = hrow[(size_t)sb.z * 64 + lane];
        unsigned p7 = hrow[(size_t)sb.w * 64 + lane];
        ax += bf2f((ushort_t)(p0 & 0xffffu)) + bf2f((ushort_t)(p1 & 0xffffu))
            + bf2f((ushort_t)(p2 & 0xffffu)) + bf2f((ushort_t)(p3 & 0xffffu))
            + bf2f((ushort_t)(p4 & 0xffffu)) + bf2f((ushort_t)(p5 & 0xffffu))
            + bf2f((ushort_t)(p6 & 0xffffu)) + bf2f((ushort_t)(p7 & 0xffffu));
        ay += bf2f((ushort_t)(p0 >> 16)) + bf2f((ushort_t)(p1 >> 16))
            + bf2f((ushort_t)(p2 >> 16)) + bf2f((ushort_t)(p3 >> 16))
            + bf2f((ushort_t)(p4 >> 16)) + bf2f((ushort_t)(p5 >> 16))
            + bf2f((ushort_t)(p6 >> 16)) + bf2f((ushort_t)(p7 >> 16));
    }
    for (; e < eend; ++e) {
        int s = csr[e];
        unsigned p = hrow[(size_t)s * 64 + lane];
        ax += bf2f((ushort_t)(p & 0xffffu));
        ay += bf2f((ushort_t)(p >> 16));
    }

    unsigned o = (unsigned)f2bf(ax) | ((unsigned)f2bf(ay) << 16);
    __builtin_nontemporal_store(o, (unsigned*)aggrb + (size_t)n * 64 + lane);
}

// ---------------- K4: out = ((1+eps)h + aggr) @ W^T + b + x  (MFMA, swapped) -----
// mfma(W_frag, T_frag) -> D[i][j] = out[row0+j][nt*16+i]: lane (l16,kg) holds
// node row l16, cols nt*16 + kg*4 + (0..3) -> float4 epilogue per nt.
__global__ __launch_bounds__(256) void gemm_mfma_kernel(
    const ushort_t* __restrict__ hb, const ushort_t* __restrict__ aggrb,
    const float* __restrict__ x, const ushort_t* __restrict__ wbf,
    const float* __restrict__ bias, const float* __restrict__ eps_p,
    float* __restrict__ out)
{
    const int wv   = threadIdx.x >> 6;
    const int lane = threadIdx.x & 63;
    const int l16  = lane & 15;
    const int kg   = lane >> 4;                 // 0..3
    const int node = blockIdx.x * 64 + wv * 16 + l16;
    const int rowc = node < N_NODES ? node : N_NODES - 1;
    const float ep1 = 1.0f + eps_p[0];

    f32x4 acc[8];
#pragma unroll
    for (int nt = 0; nt < 8; ++nt) acc[nt] = (f32x4){0.f, 0.f, 0.f, 0.f};

#pragma unroll
    for (int ks = 0; ks < 4; ++ks) {
        const int k0 = ks * 32 + kg * 8;
        // ---- T fragment (B operand): t = bf16(ep1*h + aggr), row rowc ----
        const ushort_t* hp = hb    + (size_t)rowc * D + k0;
        const ushort_t* ap = aggrb + (size_t)rowc * D + k0;
        ushort4_t h0 = *(const ushort4_t*)(hp);
        ushort4_t h1 = *(const ushort4_t*)(hp + 4);
        ushort4_t a0 = *(const ushort4_t*)(ap);
        ushort4_t a1 = *(const ushort4_t*)(ap + 4);
        bf16x8 af;
        af[0] = (short)f2bf(fmaf(ep1, bf2f(h0.x), bf2f(a0.x)));
        af[1] = (short)f2bf(fmaf(ep1, bf2f(h0.y), bf2f(a0.y)));
        af[2] = (short)f2bf(fmaf(ep1, bf2f(h0.z), bf2f(a0.z)));
        af[3] = (short)f2bf(fmaf(ep1, bf2f(h0.w), bf2f(a0.w)));
        af[4] = (short)f2bf(fmaf(ep1, bf2f(h1.x), bf2f(a1.x)));
        af[5] = (short)f2bf(fmaf(ep1, bf2f(h1.y), bf2f(a1.y)));
        af[6] = (short)f2bf(fmaf(ep1, bf2f(h1.z), bf2f(a1.z)));
        af[7] = (short)f2bf(fmaf(ep1, bf2f(h1.w), bf2f(a1.w)));

#pragma unroll
        for (int nt = 0; nt < 8; ++nt) {
            // W fragment (A operand): row nt*16 + l16 of W (bf16)
            bf16x8 bf = *(const bf16x8*)(wbf + (size_t)(nt * 16 + l16) * D + k0);
            acc[nt] = __builtin_amdgcn_mfma_f32_16x16x32_bf16(bf, af, acc[nt], 0, 0, 0);
        }
    }

    // ---- epilogue: float4 per nt — node row l16, cols nt*16 + kg*4 + (0..3) ----
    if (node < N_NODES) {
#pragma unroll
        for (int nt = 0; nt < 8; ++nt) {
            int c0 = nt * 16 + kg * 4;
            float4 bv = *(const float4*)(bias + c0);
            vf4 xv = __builtin_nontemporal_load((const vf4*)(x + (size_t)node * D + c0));
            vf4 o;
            o.x = acc[nt][0] + bv.x + xv.x;
            o.y = acc[nt][1] + bv.y + xv.y;
            o.z = acc[nt][2] + bv.z + xv.z;
            o.w = acc[nt][3] + bv.w + xv.w;
            __builtin_nontemporal_store(o, (vf4*)(out + (size_t)node * D + c0));
        }
    }
}

extern "C" void kernel_launch(void* const* d_in, const int* in_sizes, int n_in,
                              void* d_out, int out_size, void* d_ws, size_t ws_size,
                              hipStream_t stream)
{
    const float* x     = (const float*)d_in[0];
    const void*  ei    = d_in[1];
    const float* gamma = (const float*)d_in[2];
    const float* beta  = (const float*)d_in[3];
    const float* W     = (const float*)d_in[4];
    const float* bias  = (const float*)d_in[5];
    const float* eps_p = (const float*)d_in[6];
    float* out = (float*)d_out;

    char* ws = (char*)d_ws;
    size_t off = 0;
    ushort_t*  hb      = (ushort_t*)(ws + off);  off += (size_t)N_NODES * D * 2;   // 25.6 MB
    ushort_t*  aggrb   = (ushort_t*)(ws + off);  off += (size_t)N_NODES * D * 2;   // 25.6 MB
    long long* chain   = (long long*)(ws + off); off += (size_t)N_EDGES * 8;       // 12.8 MB
    int*       csr     = (int*)(ws + off);       off += (size_t)N_EDGES * 4;       //  6.4 MB
    int*       head    = (int*)(ws + off);       off += (size_t)N_NODES * 4;       //  0.4 MB
    int2*      posdeg  = (int2*)(ws + off);      off += (size_t)N_NODES * 8;       //  0.8 MB
    ushort_t*  wbf     = (ushort_t*)(ws + off);  off += (size_t)D * D * 2;         //  32 KB
    int*       cursor  = (int*)(ws + off);       off += 4;

    (void)hipMemsetAsync(head, 0xFF, (size_t)N_NODES * 4, stream);     // head = -1
    (void)hipMemsetAsync(cursor, 0, 4, stream);
    build_wbf_kernel<<<NB_CHAIN + NB_WBF, 256, 0, stream>>>(ei, chain, head, W, wbf);
    flatten_ln_kernel<<<NB_FLAT + NB_LN, 256, 0, stream>>>(
        chain, head, cursor, posdeg, csr, x, gamma, beta, hb);
    csr_segsum_kernel<<<N_NODES / 4, 256, 0, stream>>>(hb, posdeg, csr, aggrb);
    gemm_mfma_kernel<<<(N_NODES + 63) / 64, 256, 0, stream>>>(hb, aggrb, x, wbf, bias, eps_p, out);
}

// Round 12
// 264.469 us; speedup vs baseline: 1.3364x; 1.0044x over previous
//
#include <hip/hip_runtime.h>

#define N_NODES 100000
#define N_EDGES 1600000
#define D 128

// head is padded: one node per 128B line to kill atomic line-contention
#define HSTRIDE 32

typedef unsigned short ushort_t;
struct ushort4_t { ushort_t x, y, z, w; };
typedef __attribute__((ext_vector_type(8))) short bf16x8;
typedef __attribute__((ext_vector_type(4))) float f32x4;
typedef float vf4 __attribute__((ext_vector_type(4)));

#define NB_CHAIN (N_EDGES / 256)          // 6250
#define NB_WBF   16
#define NB_FLAT  ((N_NODES + 255) / 256)  // 391
#define NB_LN    (N_NODES / 8)            // 12500

__device__ __forceinline__ ushort_t f2bf(float f) {
    unsigned u = __float_as_uint(f);
    unsigned r = (u + 0x7fffu + ((u >> 16) & 1u)) >> 16;   // RNE
    return (ushort_t)r;
}
__device__ __forceinline__ float bf2f(ushort_t b) {
    return __uint_as_float(((unsigned)b) << 16);
}

// ---------------- K1: chain_build (+inline dtype detect) | wbf ------------------
// chain[e] = src | (next << 32). ONE random atomic per edge; chain store coalesced.
// head[d*HSTRIDE]: one node per 128B line -> no cross-node line contention.
__global__ __launch_bounds__(256) void build_wbf_kernel(
    const void* __restrict__ e_raw,
    long long* __restrict__ chain, int* __restrict__ head,
    const float* __restrict__ W, ushort_t* __restrict__ wbf)
{
    int b = blockIdx.x;
    if (b < NB_CHAIN) {
        // inline int64-vs-int32 detect: odd int32 words of first 64 entries all 0
        int li = threadIdx.x & 63;
        int probe = ((const int*)e_raw)[2 * li + 1];
        bool is64 = (__ballot(probe == 0) == ~0ULL);   // wave-uniform

        int e = b * 256 + threadIdx.x;                 // exactly N_EDGES threads
        int s, d;
        if (is64) {
            s = (int)__builtin_nontemporal_load(&((const long long*)e_raw)[e]);
            d = (int)__builtin_nontemporal_load(&((const long long*)e_raw)[N_EDGES + e]);
        } else {
            s = __builtin_nontemporal_load(&((const int*)e_raw)[e]);
            d = __builtin_nontemporal_load(&((const int*)e_raw)[N_EDGES + e]);
        }
        int old = atomicExch(&head[(size_t)d * HSTRIDE], e);
        chain[e] = (long long)(unsigned int)s | ((long long)old << 32);
    } else {
        // wbf: W -> bf16, 16 blocks cover 128*128
        int i = ((b - NB_CHAIN) * 256 + threadIdx.x) * 4;
        float4 w = *(const float4*)(W + i);
        ushort4_t o;
        o.x = f2bf(w.x); o.y = f2bf(w.y); o.z = f2bf(w.z); o.w = f2bf(w.w);
        *(ushort4_t*)(wbf + i) = o;
    }
}

// ---------------- K2: flatten chains -> CSR | LayerNorm+ReLU -> bf16 h ----------
// flatten: one thread per node, walk 1 counts deg, wave prefix + 1 atomic/wave
// allocates, walk 2 writes srcs. ln: streaming BW hides under flatten latency.
__global__ __launch_bounds__(256) void flatten_ln_kernel(
    const long long* __restrict__ chain, const int* __restrict__ head,
    int* __restrict__ cursor, int2* __restrict__ posdeg, int* __restrict__ csr,
    const float* __restrict__ x, const float* __restrict__ gamma,
    const float* __restrict__ beta, ushort_t* __restrict__ hb)
{
    int b = blockIdx.x;
    if (b < NB_FLAT) {
        int n    = b * 256 + threadIdx.x;
        int lane = threadIdx.x & 63;
        int e = (n < N_NODES) ? head[(size_t)n * HSTRIDE] : -1;

        // walk 1: count
        int deg = 0;
        int t = e;
        while (t != -1) {
            long long c = chain[t];
            ++deg;
            t = (int)(c >> 32);
        }

        // wave-aggregated allocation
        int psum = deg;
#pragma unroll
        for (int m = 1; m < 64; m <<= 1) {
            int v = __shfl_up(psum, m);
            if (lane >= m) psum += v;
        }
        int total = __shfl(psum, 63);
        int base = 0;
        if (lane == 0) base = atomicAdd(cursor, total);
        base = __shfl(base, 0);
        int pos = base + psum - deg;          // exclusive within wave
        if (n < N_NODES) posdeg[n] = make_int2(pos, deg);

        // walk 2: write
        int p = pos;
        while (e != -1) {
            long long c = chain[e];
            csr[p++] = (int)(unsigned int)c;
            e = (int)(c >> 32);
        }
    } else {
        int wave   = threadIdx.x >> 6;
        int half   = (threadIdx.x >> 5) & 1;
        int lane32 = threadIdx.x & 31;
        int row = (b - NB_FLAT) * 8 + wave * 2 + half;
        float4 v = ((const float4*)(x + (size_t)row * D))[lane32];
        float s  = (v.x + v.y) + (v.z + v.w);
        float sq = (v.x * v.x + v.y * v.y) + (v.z * v.z + v.w * v.w);
#pragma unroll
        for (int m = 16; m >= 1; m >>= 1) {
            s  += __shfl_xor(s, m);
            sq += __shfl_xor(sq, m);
        }
        float mu   = s * (1.0f / D);
        float var  = sq * (1.0f / D) - mu * mu;
        float rstd = rsqrtf(var + 1e-5f);
        float4 g = ((const float4*)gamma)[lane32];
        float4 bb = ((const float4*)beta)[lane32];
        ushort4_t o;
        o.x = f2bf(fmaxf(fmaf((v.x - mu) * rstd, g.x, bb.x), 0.0f));
        o.y = f2bf(fmaxf(fmaf((v.y - mu) * rstd, g.y, bb.y), 0.0f));
        o.z = f2bf(fmaxf(fmaf((v.z - mu) * rstd, g.z, bb.z), 0.0f));
        o.w = f2bf(fmaxf(fmaf((v.w - mu) * rstd, g.w, bb.w), 0.0f));
        *(ushort4_t*)(hb + (size_t)row * D + lane32 * 4) = o;
    }
}

// ---------------- K3: CSR segment sum — one wave per node, bf16 out --------------
__global__ __launch_bounds__(256) void csr_segsum_kernel(
    const ushort_t* __restrict__ hb, const int2* __restrict__ posdeg,
    const int* __restrict__ csr, ushort_t* __restrict__ aggrb)
{
    int n    = blockIdx.x * 4 + (threadIdx.x >> 6);
    int lane = threadIdx.x & 63;
    int2 pd  = posdeg[n];
    int e    = pd.x;
    int eend = pd.x + pd.y;
    const unsigned* hrow = (const unsigned*)hb;   // 64 dwords per node row
    float ax = 0.0f, ay = 0.0f;

    for (; e + 8 <= eend; e += 8) {
        int4 sa = *(const int4*)(csr + e);
        int4 sb = *(const int4*)(csr + e + 4);
        unsigned p0 = hrow[(size_t)sa.x * 64 + lane];
        unsigned p1 = hrow[(size_t)sa.y * 64 + lane];
        unsigned p2 = hrow[(size_t)sa.z * 64 + lane];
        unsigned p3 = hrow[(size_t)sa.w * 64 + lane];
        unsigned p4 = hrow[(size_t)sb.x * 64 + lane];
        unsigned p5 = hrow[(size_t)sb.y * 64 + lane];
        unsigned p6 = hrow[(size_t)sb.z * 64 + lane];
        unsigned p7 = hrow[(size_t)sb.w * 64 + lane];
        ax += bf2f((ushort_t)(p0 & 0xffffu)) + bf2f((ushort_t)(p1 & 0xffffu))
            + bf2f((ushort_t)(p2 & 0xffffu)) + bf2f((ushort_t)(p3 & 0xffffu))
            + bf2f((ushort_t)(p4 & 0xffffu)) + bf2f((ushort_t)(p5 & 0xffffu))
            + bf2f((ushort_t)(p6 & 0xffffu)) + bf2f((ushort_t)(p7 & 0xffffu));
        ay += bf2f((ushort_t)(p0 >> 16)) + bf2f((ushort_t)(p1 >> 16))
            + bf2f((ushort_t)(p2 >> 16)) + bf2f((ushort_t)(p3 >> 16))
            + bf2f((ushort_t)(p4 >> 16)) + bf2f((ushort_t)(p5 >> 16))
            + bf2f((ushort_t)(p6 >> 16)) + bf2f((ushort_t)(p7 >> 16));
    }
    for (; e < eend; ++e) {
        int s = csr[e];
        unsigned p = hrow[(size_t)s * 64 + lane];
        ax += bf2f((ushort_t)(p & 0xffffu));
        ay += bf2f((ushort_t)(p >> 16));
    }

    unsigned o = (unsigned)f2bf(ax) | ((unsigned)f2bf(ay) << 16);
    __builtin_nontemporal_store(o, (unsigned*)aggrb + (size_t)n * 64 + lane);
}

// ---------------- K4: out = ((1+eps)h + aggr) @ W^T + b + x  (MFMA, swapped) -----
// mfma(W_frag, T_frag) -> lane (l16,kg) holds node row l16, cols nt*16+kg*4+(0..3)
__global__ __launch_bounds__(256) void gemm_mfma_kernel(
    const ushort_t* __restrict__ hb, const ushort_t* __restrict__ aggrb,
    const float* __restrict__ x, const ushort_t* __restrict__ wbf,
    const float* __restrict__ bias, const float* __restrict__ eps_p,
    float* __restrict__ out)
{
    const int wv   = threadIdx.x >> 6;
    const int lane = threadIdx.x & 63;
    const int l16  = lane & 15;
    const int kg   = lane >> 4;                 // 0..3
    const int node = blockIdx.x * 64 + wv * 16 + l16;
    const int rowc = node < N_NODES ? node : N_NODES - 1;
    const float ep1 = 1.0f + eps_p[0];

    f32x4 acc[8];
#pragma unroll
    for (int nt = 0; nt < 8; ++nt) acc[nt] = (f32x4){0.f, 0.f, 0.f, 0.f};

#pragma unroll
    for (int ks = 0; ks < 4; ++ks) {
        const int k0 = ks * 32 + kg * 8;
        const ushort_t* hp = hb    + (size_t)rowc * D + k0;
        const ushort_t* ap = aggrb + (size_t)rowc * D + k0;
        ushort4_t h0 = *(const ushort4_t*)(hp);
        ushort4_t h1 = *(const ushort4_t*)(hp + 4);
        ushort4_t a0 = *(const ushort4_t*)(ap);
        ushort4_t a1 = *(const ushort4_t*)(ap + 4);
        bf16x8 af;
        af[0] = (short)f2bf(fmaf(ep1, bf2f(h0.x), bf2f(a0.x)));
        af[1] = (short)f2bf(fmaf(ep1, bf2f(h0.y), bf2f(a0.y)));
        af[2] = (short)f2bf(fmaf(ep1, bf2f(h0.z), bf2f(a0.z)));
        af[3] = (short)f2bf(fmaf(ep1, bf2f(h0.w), bf2f(a0.w)));
        af[4] = (short)f2bf(fmaf(ep1, bf2f(h1.x), bf2f(a1.x)));
        af[5] = (short)f2bf(fmaf(ep1, bf2f(h1.y), bf2f(a1.y)));
        af[6] = (short)f2bf(fmaf(ep1, bf2f(h1.z), bf2f(a1.z)));
        af[7] = (short)f2bf(fmaf(ep1, bf2f(h1.w), bf2f(a1.w)));

#pragma unroll
        for (int nt = 0; nt < 8; ++nt) {
            bf16x8 bf = *(const bf16x8*)(wbf + (size_t)(nt * 16 + l16) * D + k0);
            acc[nt] = __builtin_amdgcn_mfma_f32_16x16x32_bf16(bf, af, acc[nt], 0, 0, 0);
        }
    }

    if (node < N_NODES) {
#pragma unroll
        for (int nt = 0; nt < 8; ++nt) {
            int c0 = nt * 16 + kg * 4;
            float4 bv = *(const float4*)(bias + c0);
            vf4 xv = __builtin_nontemporal_load((const vf4*)(x + (size_t)node * D + c0));
            vf4 o;
            o.x = acc[nt][0] + bv.x + xv.x;
            o.y = acc[nt][1] + bv.y + xv.y;
            o.z = acc[nt][2] + bv.z + xv.z;
            o.w = acc[nt][3] + bv.w + xv.w;
            __builtin_nontemporal_store(o, (vf4*)(out + (size_t)node * D + c0));
        }
    }
}

extern "C" void kernel_launch(void* const* d_in, const int* in_sizes, int n_in,
                              void* d_out, int out_size, void* d_ws, size_t ws_size,
                              hipStream_t stream)
{
    const float* x     = (const float*)d_in[0];
    const void*  ei    = d_in[1];
    const float* gamma = (const float*)d_in[2];
    const float* beta  = (const float*)d_in[3];
    const float* W     = (const float*)d_in[4];
    const float* bias  = (const float*)d_in[5];
    const float* eps_p = (const float*)d_in[6];
    float* out = (float*)d_out;

    char* ws = (char*)d_ws;
    size_t off = 0;
    ushort_t*  hb      = (ushort_t*)(ws + off);  off += (size_t)N_NODES * D * 2;        // 25.6 MB
    ushort_t*  aggrb   = (ushort_t*)(ws + off);  off += (size_t)N_NODES * D * 2;        // 25.6 MB
    long long* chain   = (long long*)(ws + off); off += (size_t)N_EDGES * 8;            // 12.8 MB
    int*       csr     = (int*)(ws + off);       off += (size_t)N_EDGES * 4;            //  6.4 MB
    int*       head    = (int*)(ws + off);       off += (size_t)N_NODES * HSTRIDE * 4;  // 12.8 MB
    int2*      posdeg  = (int2*)(ws + off);      off += (size_t)N_NODES * 8;            //  0.8 MB
    ushort_t*  wbf     = (ushort_t*)(ws + off);  off += (size_t)D * D * 2;              //  32 KB
    int*       cursor  = (int*)(ws + off);       off += 4;

    (void)hipMemsetAsync(head, 0xFF, (size_t)N_NODES * HSTRIDE * 4, stream);  // head = -1
    (void)hipMemsetAsync(cursor, 0, 4, stream);
    build_wbf_kernel<<<NB_CHAIN + NB_WBF, 256, 0, stream>>>(ei, chain, head, W, wbf);
    flatten_ln_kernel<<<NB_FLAT + NB_LN, 256, 0, stream>>>(
        chain, head, cursor, posdeg, csr, x, gamma, beta, hb);
    csr_segsum_kernel<<<N_NODES / 4, 256, 0, stream>>>(hb, posdeg, csr, aggrb);
    gemm_mfma_kernel<<<(N_NODES + 63) / 64, 256, 0, stream>>>(hb, aggrb, x, wbf, bias, eps_p, out);
}

// Round 13
// 257.942 us; speedup vs baseline: 1.3702x; 1.0253x over previous
//
#include <hip/hip_runtime.h>

#define N_NODES 100000
#define N_EDGES 1600000
#define D 128

#define BUCKET  64    // slots per node; Poisson(16) => P(deg>64) ~ 1e-21
#define CSTRIDE 32    // cnt padding: one counter per 128B line
#define OVF_MAX 4096

typedef unsigned short ushort_t;
struct ushort4_t { ushort_t x, y, z, w; };
typedef __attribute__((ext_vector_type(8))) short bf16x8;
typedef __attribute__((ext_vector_type(4))) float f32x4;
typedef float vf4 __attribute__((ext_vector_type(4)));

#define NB_EDGE (N_EDGES / 256)           // 6250
#define NB_WBF  16
#define NB_LN   (N_NODES / 8)             // 12500

__device__ __forceinline__ ushort_t f2bf(float f) {
    unsigned u = __float_as_uint(f);
    unsigned r = (u + 0x7fffu + ((u >> 16) & 1u)) >> 16;   // RNE
    return (ushort_t)r;
}
__device__ __forceinline__ float bf2f(ushort_t b) {
    return __uint_as_float(((unsigned)b) << 16);
}

// ---------------- K1: bucket scatter | wbf | LayerNorm+ReLU ----------------------
// Edge part: pos = atomicAdd(cnt[d]) (one padded atomic/edge), bucket[d*64+pos]=s.
// Slots fill from 0 -> a node's ~16 srcs sit in 1-2 lines; bucket is L2-resident.
// LN and wbf ride along as extra blocks (build is atomic-latency-bound).
__global__ __launch_bounds__(256) void build_wbf_ln_kernel(
    const void* __restrict__ e_raw, int* __restrict__ cnt, int* __restrict__ bucket,
    int* __restrict__ ovf, int* __restrict__ ovf_cnt,
    const float* __restrict__ W, ushort_t* __restrict__ wbf,
    const float* __restrict__ x, const float* __restrict__ gamma,
    const float* __restrict__ beta, ushort_t* __restrict__ hb)
{
    int b = blockIdx.x;
    if (b < NB_EDGE) {
        // inline int64-vs-int32 detect: odd int32 words of first 64 entries all 0
        int li = threadIdx.x & 63;
        int probe = ((const int*)e_raw)[2 * li + 1];
        bool is64 = (__ballot(probe == 0) == ~0ULL);   // wave-uniform

        int e = b * 256 + threadIdx.x;                 // exactly N_EDGES threads
        int s, d;
        if (is64) {
            s = (int)__builtin_nontemporal_load(&((const long long*)e_raw)[e]);
            d = (int)__builtin_nontemporal_load(&((const long long*)e_raw)[N_EDGES + e]);
        } else {
            s = __builtin_nontemporal_load(&((const int*)e_raw)[e]);
            d = __builtin_nontemporal_load(&((const int*)e_raw)[N_EDGES + e]);
        }
        int pos = atomicAdd(&cnt[(size_t)d * CSTRIDE], 1);
        if (pos < BUCKET) {
            bucket[(size_t)d * BUCKET + pos] = s;
        } else {
            int op = atomicAdd(ovf_cnt, 1);            // essentially never
            if (op < OVF_MAX) { ovf[op * 2] = d; ovf[op * 2 + 1] = s; }
        }
    } else if (b < NB_EDGE + NB_WBF) {
        // wbf: W -> bf16, 16 blocks cover 128*128
        int i = ((b - NB_EDGE) * 256 + threadIdx.x) * 4;
        float4 w = *(const float4*)(W + i);
        ushort4_t o;
        o.x = f2bf(w.x); o.y = f2bf(w.y); o.z = f2bf(w.z); o.w = f2bf(w.w);
        *(ushort4_t*)(wbf + i) = o;
    } else {
        int wave   = threadIdx.x >> 6;
        int half   = (threadIdx.x >> 5) & 1;
        int lane32 = threadIdx.x & 31;
        int row = (b - NB_EDGE - NB_WBF) * 8 + wave * 2 + half;
        float4 v = ((const float4*)(x + (size_t)row * D))[lane32];
        float s  = (v.x + v.y) + (v.z + v.w);
        float sq = (v.x * v.x + v.y * v.y) + (v.z * v.z + v.w * v.w);
#pragma unroll
        for (int m = 16; m >= 1; m >>= 1) {
            s  += __shfl_xor(s, m);
            sq += __shfl_xor(sq, m);
        }
        float mu   = s * (1.0f / D);
        float var  = sq * (1.0f / D) - mu * mu;
        float rstd = rsqrtf(var + 1e-5f);
        float4 g = ((const float4*)gamma)[lane32];
        float4 bb = ((const float4*)beta)[lane32];
        ushort4_t o;
        o.x = f2bf(fmaxf(fmaf((v.x - mu) * rstd, g.x, bb.x), 0.0f));
        o.y = f2bf(fmaxf(fmaf((v.y - mu) * rstd, g.y, bb.y), 0.0f));
        o.z = f2bf(fmaxf(fmaf((v.z - mu) * rstd, g.z, bb.z), 0.0f));
        o.w = f2bf(fmaxf(fmaf((v.w - mu) * rstd, g.w, bb.w), 0.0f));
        *(ushort4_t*)(hb + (size_t)row * D + lane32 * 4) = o;
    }
}

// ---------------- K2: bucket segment sum — one wave per node, bf16 out -----------
// Segment for node n: bucket[n*64 .. n*64+deg), 256B-aligned -> int4 reads OK.
__global__ __launch_bounds__(256) void bucket_segsum_kernel(
    const ushort_t* __restrict__ hb, const int* __restrict__ cnt,
    const int* __restrict__ bucket, const int* __restrict__ ovf,
    const int* __restrict__ ovf_cnt, ushort_t* __restrict__ aggrb)
{
    int n    = blockIdx.x * 4 + (threadIdx.x >> 6);
    int lane = threadIdx.x & 63;
    int deg  = cnt[(size_t)n * CSTRIDE];
    int eend = deg < BUCKET ? deg : BUCKET;
    const int* seg = bucket + (size_t)n * BUCKET;
    const unsigned* hrow = (const unsigned*)hb;   // 64 dwords per node row
    float ax = 0.0f, ay = 0.0f;
    int e = 0;

    for (; e + 8 <= eend; e += 8) {
        int4 sa = *(const int4*)(seg + e);
        int4 sb = *(const int4*)(seg + e + 4);
        unsigned p0 = hrow[(size_t)sa.x * 64 + lane];
        unsigned p1 = hrow[(size_t)sa.y * 64 + lane];
        unsigned p2 = hrow[(size_t)sa.z * 64 + lane];
        unsigned p3 = hrow[(size_t)sa.w * 64 + lane];
        unsigned p4 = hrow[(size_t)sb.x * 64 + lane];
        unsigned p5 = hrow[(size_t)sb.y * 64 + lane];
        unsigned p6 = hrow[(size_t)sb.z * 64 + lane];
        unsigned p7 = hrow[(size_t)sb.w * 64 + lane];
        ax += bf2f((ushort_t)(p0 & 0xffffu)) + bf2f((ushort_t)(p1 & 0xffffu))
            + bf2f((ushort_t)(p2 & 0xffffu)) + bf2f((ushort_t)(p3 & 0xffffu))
            + bf2f((ushort_t)(p4 & 0xffffu)) + bf2f((ushort_t)(p5 & 0xffffu))
            + bf2f((ushort_t)(p6 & 0xffffu)) + bf2f((ushort_t)(p7 & 0xffffu));
        ay += bf2f((ushort_t)(p0 >> 16)) + bf2f((ushort_t)(p1 >> 16))
            + bf2f((ushort_t)(p2 >> 16)) + bf2f((ushort_t)(p3 >> 16))
            + bf2f((ushort_t)(p4 >> 16)) + bf2f((ushort_t)(p5 >> 16))
            + bf2f((ushort_t)(p6 >> 16)) + bf2f((ushort_t)(p7 >> 16));
    }
    for (; e < eend; ++e) {
        int s = seg[e];
        unsigned p = hrow[(size_t)s * 64 + lane];
        ax += bf2f((ushort_t)(p & 0xffffu));
        ay += bf2f((ushort_t)(p >> 16));
    }

    // overflow entries (count ~0; wave-uniform branch)
    int oc = *ovf_cnt;
    if (oc > 0) {
        oc = oc < OVF_MAX ? oc : OVF_MAX;
        for (int i = 0; i < oc; ++i) {
            if (ovf[2 * i] == n) {
                unsigned p = hrow[(size_t)ovf[2 * i + 1] * 64 + lane];
                ax += bf2f((ushort_t)(p & 0xffffu));
                ay += bf2f((ushort_t)(p >> 16));
            }
        }
    }

    unsigned o = (unsigned)f2bf(ax) | ((unsigned)f2bf(ay) << 16);
    __builtin_nontemporal_store(o, (unsigned*)aggrb + (size_t)n * 64 + lane);
}

// ---------------- K3: out = ((1+eps)h + aggr) @ W^T + b + x  (MFMA, swapped) -----
// mfma(W_frag, T_frag) -> lane (l16,kg) holds node row l16, cols nt*16+kg*4+(0..3)
__global__ __launch_bounds__(256) void gemm_mfma_kernel(
    const ushort_t* __restrict__ hb, const ushort_t* __restrict__ aggrb,
    const float* __restrict__ x, const ushort_t* __restrict__ wbf,
    const float* __restrict__ bias, const float* __restrict__ eps_p,
    float* __restrict__ out)
{
    const int wv   = threadIdx.x >> 6;
    const int lane = threadIdx.x & 63;
    const int l16  = lane & 15;
    const int kg   = lane >> 4;                 // 0..3
    const int node = blockIdx.x * 64 + wv * 16 + l16;
    const int rowc = node < N_NODES ? node : N_NODES - 1;
    const float ep1 = 1.0f + eps_p[0];

    f32x4 acc[8];
#pragma unroll
    for (int nt = 0; nt < 8; ++nt) acc[nt] = (f32x4){0.f, 0.f, 0.f, 0.f};

#pragma unroll
    for (int ks = 0; ks < 4; ++ks) {
        const int k0 = ks * 32 + kg * 8;
        const ushort_t* hp = hb    + (size_t)rowc * D + k0;
        const ushort_t* ap = aggrb + (size_t)rowc * D + k0;
        ushort4_t h0 = *(const ushort4_t*)(hp);
        ushort4_t h1 = *(const ushort4_t*)(hp + 4);
        ushort4_t a0 = *(const ushort4_t*)(ap);
        ushort4_t a1 = *(const ushort4_t*)(ap + 4);
        bf16x8 af;
        af[0] = (short)f2bf(fmaf(ep1, bf2f(h0.x), bf2f(a0.x)));
        af[1] = (short)f2bf(fmaf(ep1, bf2f(h0.y), bf2f(a0.y)));
        af[2] = (short)f2bf(fmaf(ep1, bf2f(h0.z), bf2f(a0.z)));
        af[3] = (short)f2bf(fmaf(ep1, bf2f(h0.w), bf2f(a0.w)));
        af[4] = (short)f2bf(fmaf(ep1, bf2f(h1.x), bf2f(a1.x)));
        af[5] = (short)f2bf(fmaf(ep1, bf2f(h1.y), bf2f(a1.y)));
        af[6] = (short)f2bf(fmaf(ep1, bf2f(h1.z), bf2f(a1.z)));
        af[7] = (short)f2bf(fmaf(ep1, bf2f(h1.w), bf2f(a1.w)));

#pragma unroll
        for (int nt = 0; nt < 8; ++nt) {
            bf16x8 bf = *(const bf16x8*)(wbf + (size_t)(nt * 16 + l16) * D + k0);
            acc[nt] = __builtin_amdgcn_mfma_f32_16x16x32_bf16(bf, af, acc[nt], 0, 0, 0);
        }
    }

    if (node < N_NODES) {
#pragma unroll
        for (int nt = 0; nt < 8; ++nt) {
            int c0 = nt * 16 + kg * 4;
            float4 bv = *(const float4*)(bias + c0);
            vf4 xv = __builtin_nontemporal_load((const vf4*)(x + (size_t)node * D + c0));
            vf4 o;
            o.x = acc[nt][0] + bv.x + xv.x;
            o.y = acc[nt][1] + bv.y + xv.y;
            o.z = acc[nt][2] + bv.z + xv.z;
            o.w = acc[nt][3] + bv.w + xv.w;
            __builtin_nontemporal_store(o, (vf4*)(out + (size_t)node * D + c0));
        }
    }
}

extern "C" void kernel_launch(void* const* d_in, const int* in_sizes, int n_in,
                              void* d_out, int out_size, void* d_ws, size_t ws_size,
                              hipStream_t stream)
{
    const float* x     = (const float*)d_in[0];
    const void*  ei    = d_in[1];
    const float* gamma = (const float*)d_in[2];
    const float* beta  = (const float*)d_in[3];
    const float* W     = (const float*)d_in[4];
    const float* bias  = (const float*)d_in[5];
    const float* eps_p = (const float*)d_in[6];
    float* out = (float*)d_out;

    char* ws = (char*)d_ws;
    size_t off = 0;
    ushort_t* hb      = (ushort_t*)(ws + off); off += (size_t)N_NODES * D * 2;        // 25.6 MB
    ushort_t* aggrb   = (ushort_t*)(ws + off); off += (size_t)N_NODES * D * 2;        // 25.6 MB
    int*      bucket  = (int*)(ws + off);      off += (size_t)N_NODES * BUCKET * 4;   // 25.6 MB
    int*      cnt     = (int*)(ws + off);      off += (size_t)N_NODES * CSTRIDE * 4;  // 12.8 MB
    ushort_t* wbf     = (ushort_t*)(ws + off); off += (size_t)D * D * 2;              //  32 KB
    int*      ovf     = (int*)(ws + off);      off += (size_t)OVF_MAX * 2 * 4;        //  32 KB
    int*      ovf_cnt = (int*)(ws + off);      off += 4;

    (void)hipMemsetAsync(cnt, 0, (size_t)N_NODES * CSTRIDE * 4, stream);
    (void)hipMemsetAsync(ovf_cnt, 0, 4, stream);
    build_wbf_ln_kernel<<<NB_EDGE + NB_WBF + NB_LN, 256, 0, stream>>>(
        ei, cnt, bucket, ovf, ovf_cnt, W, wbf, x, gamma, beta, hb);
    bucket_segsum_kernel<<<N_NODES / 4, 256, 0, stream>>>(hb, cnt, bucket, ovf, ovf_cnt, aggrb);
    gemm_mfma_kernel<<<(N_NODES + 63) / 64, 256, 0, stream>>>(hb, aggrb, x, wbf, bias, eps_p, out);
}

// Round 14
// 233.847 us; speedup vs baseline: 1.5114x; 1.1030x over previous
//
#include <hip/hip_runtime.h>

#define N_NODES 100000
#define N_EDGES 1600000
#define D 128

#define NSLOT   72    // ints per node region (288B, 16B-aligned); [0]=cnt, [4..71]=srcs
#define CAP     68
#define OVF_MAX 4096

typedef unsigned short ushort_t;
struct ushort4_t { ushort_t x, y, z, w; };
typedef __attribute__((ext_vector_type(8))) short bf16x8;
typedef __attribute__((ext_vector_type(4))) float f32x4;
typedef float vf4 __attribute__((ext_vector_type(4)));

#define NB_EDGE (N_EDGES / 256)           // 6250
#define NB_WBF  16
#define NB_LN   (N_NODES / 8)             // 12500

__device__ __forceinline__ ushort_t f2bf(float f) {
    unsigned u = __float_as_uint(f);
    unsigned r = (u + 0x7fffu + ((u >> 16) & 1u)) >> 16;   // RNE
    return (ushort_t)r;
}
__device__ __forceinline__ float bf2f(ushort_t b) {
    return __uint_as_float(((unsigned)b) << 16);
}

// ---------------- K1: bucket scatter (inline cnt) | wbf | LayerNorm+ReLU ---------
// pos = atomicAdd(&bucket[d*72]) pulls the region's line into its home L2; the
// dependent src store hits the SAME hot line -> one random line touch per edge.
__global__ __launch_bounds__(256) void build_wbf_ln_kernel(
    const void* __restrict__ e_raw, int* __restrict__ bucket,
    int* __restrict__ ovf, int* __restrict__ ovf_cnt,
    const float* __restrict__ W, ushort_t* __restrict__ wbf,
    const float* __restrict__ x, const float* __restrict__ gamma,
    const float* __restrict__ beta, ushort_t* __restrict__ hb)
{
    int b = blockIdx.x;
    if (b < NB_EDGE) {
        // inline int64-vs-int32 detect: odd int32 words of first 64 entries all 0
        int li = threadIdx.x & 63;
        int probe = ((const int*)e_raw)[2 * li + 1];
        bool is64 = (__ballot(probe == 0) == ~0ULL);   // wave-uniform

        int e = b * 256 + threadIdx.x;                 // exactly N_EDGES threads
        int s, d;
        if (is64) {
            s = (int)__builtin_nontemporal_load(&((const long long*)e_raw)[e]);
            d = (int)__builtin_nontemporal_load(&((const long long*)e_raw)[N_EDGES + e]);
        } else {
            s = __builtin_nontemporal_load(&((const int*)e_raw)[e]);
            d = __builtin_nontemporal_load(&((const int*)e_raw)[N_EDGES + e]);
        }
        int* reg = bucket + (size_t)d * NSLOT;
        int pos = atomicAdd(reg, 1);
        if (pos < CAP) {
            reg[4 + pos] = s;                          // same line as the atomic
        } else {
            int op = atomicAdd(ovf_cnt, 1);            // essentially never
            if (op < OVF_MAX) { ovf[op * 2] = d; ovf[op * 2 + 1] = s; }
        }
    } else if (b < NB_EDGE + NB_WBF) {
        // wbf: W -> bf16, 16 blocks cover 128*128
        int i = ((b - NB_EDGE) * 256 + threadIdx.x) * 4;
        float4 w = *(const float4*)(W + i);
        ushort4_t o;
        o.x = f2bf(w.x); o.y = f2bf(w.y); o.z = f2bf(w.z); o.w = f2bf(w.w);
        *(ushort4_t*)(wbf + i) = o;
    } else {
        int wave   = threadIdx.x >> 6;
        int half   = (threadIdx.x >> 5) & 1;
        int lane32 = threadIdx.x & 31;
        int row = (b - NB_EDGE - NB_WBF) * 8 + wave * 2 + half;
        float4 v = ((const float4*)(x + (size_t)row * D))[lane32];
        float s  = (v.x + v.y) + (v.z + v.w);
        float sq = (v.x * v.x + v.y * v.y) + (v.z * v.z + v.w * v.w);
#pragma unroll
        for (int m = 16; m >= 1; m >>= 1) {
            s  += __shfl_xor(s, m);
            sq += __shfl_xor(sq, m);
        }
        float mu   = s * (1.0f / D);
        float var  = sq * (1.0f / D) - mu * mu;
        float rstd = rsqrtf(var + 1e-5f);
        float4 g = ((const float4*)gamma)[lane32];
        float4 bb = ((const float4*)beta)[lane32];
        ushort4_t o;
        o.x = f2bf(fmaxf(fmaf((v.x - mu) * rstd, g.x, bb.x), 0.0f));
        o.y = f2bf(fmaxf(fmaf((v.y - mu) * rstd, g.y, bb.y), 0.0f));
        o.z = f2bf(fmaxf(fmaf((v.z - mu) * rstd, g.z, bb.z), 0.0f));
        o.w = f2bf(fmaxf(fmaf((v.w - mu) * rstd, g.w, bb.w), 0.0f));
        *(ushort4_t*)(hb + (size_t)row * D + lane32 * 4) = o;
    }
}

// ---------------- K2: bucket segment sum — one wave per node, bf16 out -----------
// Node n: deg = bucket[n*72], srcs = bucket[n*72+4 ..], data 16B-aligned.
__global__ __launch_bounds__(256) void bucket_segsum_kernel(
    const ushort_t* __restrict__ hb, const int* __restrict__ bucket,
    const int* __restrict__ ovf, const int* __restrict__ ovf_cnt,
    ushort_t* __restrict__ aggrb)
{
    int n    = blockIdx.x * 4 + (threadIdx.x >> 6);
    int lane = threadIdx.x & 63;
    const int* reg = bucket + (size_t)n * NSLOT;
    int deg  = reg[0];
    int eend = deg < CAP ? deg : CAP;
    const int* seg = reg + 4;
    const unsigned* hrow = (const unsigned*)hb;   // 64 dwords per node row
    float ax = 0.0f, ay = 0.0f;
    int e = 0;

    for (; e + 8 <= eend; e += 8) {
        int4 sa = *(const int4*)(seg + e);
        int4 sb = *(const int4*)(seg + e + 4);
        unsigned p0 = hrow[(size_t)sa.x * 64 + lane];
        unsigned p1 = hrow[(size_t)sa.y * 64 + lane];
        unsigned p2 = hrow[(size_t)sa.z * 64 + lane];
        unsigned p3 = hrow[(size_t)sa.w * 64 + lane];
        unsigned p4 = hrow[(size_t)sb.x * 64 + lane];
        unsigned p5 = hrow[(size_t)sb.y * 64 + lane];
        unsigned p6 = hrow[(size_t)sb.z * 64 + lane];
        unsigned p7 = hrow[(size_t)sb.w * 64 + lane];
        ax += bf2f((ushort_t)(p0 & 0xffffu)) + bf2f((ushort_t)(p1 & 0xffffu))
            + bf2f((ushort_t)(p2 & 0xffffu)) + bf2f((ushort_t)(p3 & 0xffffu))
            + bf2f((ushort_t)(p4 & 0xffffu)) + bf2f((ushort_t)(p5 & 0xffffu))
            + bf2f((ushort_t)(p6 & 0xffffu)) + bf2f((ushort_t)(p7 & 0xffffu));
        ay += bf2f((ushort_t)(p0 >> 16)) + bf2f((ushort_t)(p1 >> 16))
            + bf2f((ushort_t)(p2 >> 16)) + bf2f((ushort_t)(p3 >> 16))
            + bf2f((ushort_t)(p4 >> 16)) + bf2f((ushort_t)(p5 >> 16))
            + bf2f((ushort_t)(p6 >> 16)) + bf2f((ushort_t)(p7 >> 16));
    }
    for (; e < eend; ++e) {
        int s = seg[e];
        unsigned p = hrow[(size_t)s * 64 + lane];
        ax += bf2f((ushort_t)(p & 0xffffu));
        ay += bf2f((ushort_t)(p >> 16));
    }

    // overflow entries (count ~0; wave-uniform branch)
    int oc = *ovf_cnt;
    if (oc > 0) {
        oc = oc < OVF_MAX ? oc : OVF_MAX;
        for (int i = 0; i < oc; ++i) {
            if (ovf[2 * i] == n) {
                unsigned p = hrow[(size_t)ovf[2 * i + 1] * 64 + lane];
                ax += bf2f((ushort_t)(p & 0xffffu));
                ay += bf2f((ushort_t)(p >> 16));
            }
        }
    }

    unsigned o = (unsigned)f2bf(ax) | ((unsigned)f2bf(ay) << 16);
    __builtin_nontemporal_store(o, (unsigned*)aggrb + (size_t)n * 64 + lane);
}

// ---------------- K3: out = ((1+eps)h + aggr) @ W^T + b + x  (MFMA, swapped) -----
// mfma(W_frag, T_frag) -> lane (l16,kg) holds node row l16, cols nt*16+kg*4+(0..3)
__global__ __launch_bounds__(256) void gemm_mfma_kernel(
    const ushort_t* __restrict__ hb, const ushort_t* __restrict__ aggrb,
    const float* __restrict__ x, const ushort_t* __restrict__ wbf,
    const float* __restrict__ bias, const float* __restrict__ eps_p,
    float* __restrict__ out)
{
    const int wv   = threadIdx.x >> 6;
    const int lane = threadIdx.x & 63;
    const int l16  = lane & 15;
    const int kg   = lane >> 4;                 // 0..3
    const int node = blockIdx.x * 64 + wv * 16 + l16;
    const int rowc = node < N_NODES ? node : N_NODES - 1;
    const float ep1 = 1.0f + eps_p[0];

    f32x4 acc[8];
#pragma unroll
    for (int nt = 0; nt < 8; ++nt) acc[nt] = (f32x4){0.f, 0.f, 0.f, 0.f};

#pragma unroll
    for (int ks = 0; ks < 4; ++ks) {
        const int k0 = ks * 32 + kg * 8;
        const ushort_t* hp = hb    + (size_t)rowc * D + k0;
        const ushort_t* ap = aggrb + (size_t)rowc * D + k0;
        ushort4_t h0 = *(const ushort4_t*)(hp);
        ushort4_t h1 = *(const ushort4_t*)(hp + 4);
        ushort4_t a0 = *(const ushort4_t*)(ap);
        ushort4_t a1 = *(const ushort4_t*)(ap + 4);
        bf16x8 af;
        af[0] = (short)f2bf(fmaf(ep1, bf2f(h0.x), bf2f(a0.x)));
        af[1] = (short)f2bf(fmaf(ep1, bf2f(h0.y), bf2f(a0.y)));
        af[2] = (short)f2bf(fmaf(ep1, bf2f(h0.z), bf2f(a0.z)));
        af[3] = (short)f2bf(fmaf(ep1, bf2f(h0.w), bf2f(a0.w)));
        af[4] = (short)f2bf(fmaf(ep1, bf2f(h1.x), bf2f(a1.x)));
        af[5] = (short)f2bf(fmaf(ep1, bf2f(h1.y), bf2f(a1.y)));
        af[6] = (short)f2bf(fmaf(ep1, bf2f(h1.z), bf2f(a1.z)));
        af[7] = (short)f2bf(fmaf(ep1, bf2f(h1.w), bf2f(a1.w)));

#pragma unroll
        for (int nt = 0; nt < 8; ++nt) {
            bf16x8 bf = *(const bf16x8*)(wbf + (size_t)(nt * 16 + l16) * D + k0);
            acc[nt] = __builtin_amdgcn_mfma_f32_16x16x32_bf16(bf, af, acc[nt], 0, 0, 0);
        }
    }

    if (node < N_NODES) {
#pragma unroll
        for (int nt = 0; nt < 8; ++nt) {
            int c0 = nt * 16 + kg * 4;
            float4 bv = *(const float4*)(bias + c0);
            vf4 xv = __builtin_nontemporal_load((const vf4*)(x + (size_t)node * D + c0));
            vf4 o;
            o.x = acc[nt][0] + bv.x + xv.x;
            o.y = acc[nt][1] + bv.y + xv.y;
            o.z = acc[nt][2] + bv.z + xv.z;
            o.w = acc[nt][3] + bv.w + xv.w;
            __builtin_nontemporal_store(o, (vf4*)(out + (size_t)node * D + c0));
        }
    }
}

extern "C" void kernel_launch(void* const* d_in, const int* in_sizes, int n_in,
                              void* d_out, int out_size, void* d_ws, size_t ws_size,
                              hipStream_t stream)
{
    const float* x     = (const float*)d_in[0];
    const void*  ei    = d_in[1];
    const float* gamma = (const float*)d_in[2];
    const float* beta  = (const float*)d_in[3];
    const float* W     = (const float*)d_in[4];
    const float* bias  = (const float*)d_in[5];
    const float* eps_p = (const float*)d_in[6];
    float* out = (float*)d_out;

    char* ws = (char*)d_ws;
    size_t off = 0;
    ushort_t* hb      = (ushort_t*)(ws + off); off += (size_t)N_NODES * D * 2;       // 25.6 MB
    ushort_t* aggrb   = (ushort_t*)(ws + off); off += (size_t)N_NODES * D * 2;       // 25.6 MB
    int*      bucket  = (int*)(ws + off);      off += (size_t)N_NODES * NSLOT * 4;   // 28.8 MB
    ushort_t* wbf     = (ushort_t*)(ws + off); off += (size_t)D * D * 2;             //  32 KB
    int*      ovf     = (int*)(ws + off);      off += (size_t)OVF_MAX * 2 * 4;       //  32 KB
    int*      ovf_cnt = (int*)(ws + off);      off += 4;

    (void)hipMemsetAsync(bucket, 0, (size_t)N_NODES * NSLOT * 4, stream);  // zero cnts
    (void)hipMemsetAsync(ovf_cnt, 0, 4, stream);
    build_wbf_ln_kernel<<<NB_EDGE + NB_WBF + NB_LN, 256, 0, stream>>>(
        ei, bucket, ovf, ovf_cnt, W, wbf, x, gamma, beta, hb);
    bucket_segsum_kernel<<<N_NODES / 4, 256, 0, stream>>>(hb, bucket, ovf, ovf_cnt, aggrb);
    gemm_mfma_kernel<<<(N_NODES + 63) / 64, 256, 0, stream>>>(hb, aggrb, x, wbf, bias, eps_p, out);
}